// Round 1
// baseline (583.252 us; speedup 1.0000x reference)
//
#include <hip/hip_runtime.h>
#include <math.h>

// Problem constants: B=2, C=256, DM=512, H=8, D=64, SPARSE_K=64
#define ROWS_PER_BH 256   // C
#define HEAD_D 64

// ---------------------------------------------------------------------------
// Generic C = A @ W^T + bias.  A: M x 512 row-major. W: 512 x 512 row-major
// (output col n uses W row n -> both A and W stream along k contiguously).
// blockIdx.z selects among up to 3 (W, bias, out) triples (QKV fusion).
// heads_mode=1: scatter output (b,c,E) -> q[b][h][c][d] layout.
// ---------------------------------------------------------------------------
__global__ __launch_bounds__(256) void mm_nt_kernel(
    const float* __restrict__ A,
    const float* __restrict__ Wa, const float* __restrict__ ba, float* __restrict__ outa,
    const float* __restrict__ Wb, const float* __restrict__ bb, float* __restrict__ outb,
    const float* __restrict__ Wc, const float* __restrict__ bc, float* __restrict__ outc,
    int heads_mode)
{
    const float* W = Wa; const float* bias = ba; float* out = outa;
    if (blockIdx.z == 1) { W = Wb; bias = bb; out = outb; }
    if (blockIdx.z == 2) { W = Wc; bias = bc; out = outc; }

    __shared__ float As[16][64];   // [k][m]
    __shared__ float Ws[16][64];   // [k][n]

    const int m0 = blockIdx.y * 64;
    const int n0 = blockIdx.x * 64;
    const int t  = threadIdx.x;
    const int tx = t & 15;         // n micro-tile
    const int ty = t >> 4;         // m micro-tile
    const int lr = t >> 2;         // 0..63 row within the 64-row tile
    const int lc = (t & 3) * 4;    // 0,4,8,12 k-offset within 16-wide k tile

    float acc[4][4] = {};

    for (int k0 = 0; k0 < 512; k0 += 16) {
        float4 av = *(const float4*)&A[(m0 + lr) * 512 + k0 + lc];
        float4 wv = *(const float4*)&W[(n0 + lr) * 512 + k0 + lc];
        As[lc + 0][lr] = av.x; As[lc + 1][lr] = av.y;
        As[lc + 2][lr] = av.z; As[lc + 3][lr] = av.w;
        Ws[lc + 0][lr] = wv.x; Ws[lc + 1][lr] = wv.y;
        Ws[lc + 2][lr] = wv.z; Ws[lc + 3][lr] = wv.w;
        __syncthreads();
        #pragma unroll
        for (int kk = 0; kk < 16; kk++) {
            float a4[4], w4[4];
            #pragma unroll
            for (int u = 0; u < 4; u++) a4[u] = As[kk][ty * 4 + u];
            #pragma unroll
            for (int u = 0; u < 4; u++) w4[u] = Ws[kk][tx * 4 + u];
            #pragma unroll
            for (int um = 0; um < 4; um++)
                #pragma unroll
                for (int un = 0; un < 4; un++)
                    acc[um][un] = fmaf(a4[um], w4[un], acc[um][un]);
        }
        __syncthreads();
    }

    #pragma unroll
    for (int um = 0; um < 4; um++) {
        int m = m0 + ty * 4 + um;
        #pragma unroll
        for (int un = 0; un < 4; un++) {
            int n = n0 + tx * 4 + un;
            float val = acc[um][un] + bias[n];
            if (heads_mode) {
                int b = m >> 8, c = m & 255, h = n >> 6, d = n & 63;
                out[(((b << 3) + h) * 256 + c) * 64 + d] = val;
            } else {
                out[m * 512 + n] = val;
            }
        }
    }
}

// ---------------------------------------------------------------------------
// q_pb[row,e] = b1[e] + sum_d q[row,d] * w1[e,d]          (w1 slice [:, :64])
// k_p [row,e] =         sum_d k[row,d] * w1[e,64+d]       (w1 slice [:, 64:128])
// rows = B*H*C = 4096. One thread per (row, e). q/k row reads are
// wave-uniform (64 consecutive lanes share a row) -> scalar loads.
// ---------------------------------------------------------------------------
__global__ __launch_bounds__(256) void qp_kp_kernel(
    const float* __restrict__ q, const float* __restrict__ k,
    const float* __restrict__ w1, const float* __restrict__ b1,
    float* __restrict__ qpb, float* __restrict__ kp)
{
    int idx = blockIdx.x * 256 + threadIdx.x;
    int row = idx >> 6, e = idx & 63;
    const float* qrow = q + row * 64;
    const float* krow = k + row * 64;
    const float* wa = w1 + e * 192;       // w1[e, d]
    const float* wb = wa + 64;            // w1[e, 64+d]
    float accq = 0.f, acck = 0.f;
    #pragma unroll 8
    for (int d = 0; d < 64; d++) {
        accq = fmaf(qrow[d], wa[d], accq);
        acck = fmaf(krow[d], wb[d], acck);
    }
    qpb[idx] = accq + b1[e];
    kp[idx]  = acck;
}

// ---------------------------------------------------------------------------
// Fused: second-order scores -> top-64 threshold -> softmax -> attn @ V.
// Grid: (i=0..255, bh=0..15), 256 threads; thread j owns key/column j.
// All of q_i, qpb_i, w1c, w2, b2 are block-uniform -> compiler scalarizes
// those loads (s_load) so the 64x64 matvec inner loop is v_fmac(v, s, v).
// ---------------------------------------------------------------------------
__global__ __launch_bounds__(256) void fused_attn_kernel(
    const float* __restrict__ q, const float* __restrict__ k, const float* __restrict__ v,
    const float* __restrict__ qpb, const float* __restrict__ kp,
    const float* __restrict__ w1, const float* __restrict__ w2, const float* __restrict__ b2,
    float* __restrict__ oa)
{
    const int i  = blockIdx.x;    // query index within (b,h)
    const int bh = blockIdx.y;    // b*8 + h
    const int t  = threadIdx.x;

    __shared__ float sc[256];
    __shared__ float red[4][64];
    __shared__ float thresh_s;

    const int row_i = bh * ROWS_PER_BH + i;
    const float* qrow   = q   + row_i * HEAD_D;   // uniform
    const float* qpbrow = qpb + row_i * HEAD_D;   // uniform

    const int j = t;
    const float* krow  = k  + (bh * ROWS_PER_BH + j) * HEAD_D;
    const float* kprow = kp + (bh * ROWS_PER_BH + j) * HEAD_D;

    // prod[e] = q_i[e] * k_j[e]
    float prod[64];
    #pragma unroll
    for (int e4 = 0; e4 < 16; e4++) {
        float4 kv = *(const float4*)(krow + e4 * 4);
        prod[e4 * 4 + 0] = kv.x * qrow[e4 * 4 + 0];
        prod[e4 * 4 + 1] = kv.y * qrow[e4 * 4 + 1];
        prod[e4 * 4 + 2] = kv.z * qrow[e4 * 4 + 2];
        prod[e4 * 4 + 3] = kv.w * qrow[e4 * 4 + 3];
    }

    // score_j = (b2 + sum_f w2[f] * gelu(qpb_i[f] + kp_j[f] + sum_e w1c[f,e]*prod[e])) / 8
    const float* wc = w1 + 128;   // w1c[f,e] = w1[f*192 + 128 + e]
    float score = 0.f;
    for (int f4 = 0; f4 < 16; f4++) {
        float4 kp4 = *(const float4*)(kprow + f4 * 4);
        float kpa[4] = {kp4.x, kp4.y, kp4.z, kp4.w};
        #pragma unroll
        for (int fi = 0; fi < 4; fi++) {
            int f = f4 * 4 + fi;
            const float* wrow = wc + f * 192;   // uniform row -> s_loads
            float mv0 = 0.f, mv1 = 0.f, mv2 = 0.f, mv3 = 0.f;
            #pragma unroll
            for (int e = 0; e < 64; e += 4) {
                mv0 = fmaf(wrow[e + 0], prod[e + 0], mv0);
                mv1 = fmaf(wrow[e + 1], prod[e + 1], mv1);
                mv2 = fmaf(wrow[e + 2], prod[e + 2], mv2);
                mv3 = fmaf(wrow[e + 3], prod[e + 3], mv3);
            }
            float r = qpbrow[f] + kpa[fi] + ((mv0 + mv1) + (mv2 + mv3));
            float g = 0.5f * r * (1.0f + erff(r * 0.70710678118654752440f));
            score = fmaf(w2[f], g, score);
        }
    }
    score = (score + b2[0]) * 0.125f;   // / sqrt(64)
    sc[j] = score;
    __syncthreads();

    // top-64 threshold: value t with #{>t} < 64 and #{>=t} >= 64 (tie-exact
    // match of jax top_k + (scores >= thresh)). Also row max for softmax.
    int cnt = 0, eq = 0;
    float smax = -3.0e38f;
    for (int m4 = 0; m4 < 64; m4++) {
        float4 s4 = *(const float4*)&sc[m4 * 4];
        cnt += (s4.x > score) + (s4.y > score) + (s4.z > score) + (s4.w > score);
        eq  += (s4.x == score) + (s4.y == score) + (s4.z == score) + (s4.w == score);
        smax = fmaxf(smax, fmaxf(fmaxf(s4.x, s4.y), fmaxf(s4.z, s4.w)));
    }
    if (cnt < 64 && cnt + eq >= 64) thresh_s = score;  // benign multi-write: same value
    __syncthreads();

    const float thr = thresh_s;
    float p = (score >= thr) ? __expf(score - smax) : 0.0f;
    sc[j] = p;          // safe: all count-loop reads completed before the barrier above
    __syncthreads();

    float psum = 0.f;
    for (int m4 = 0; m4 < 64; m4++) {
        float4 s4 = *(const float4*)&sc[m4 * 4];
        psum += (s4.x + s4.y) + (s4.z + s4.w);
    }
    const float inv = 1.0f / psum;

    // out_i[d] = inv * sum_j p_j * v[j,d]; thread t -> (d = t&63, j-chunk g = t>>6)
    const int d = t & 63, g = t >> 6;
    const float* vb = v + bh * ROWS_PER_BH * HEAD_D;
    float acc = 0.f;
    for (int jj = g * 64; jj < g * 64 + 64; jj++) {
        acc = fmaf(sc[jj], vb[jj * 64 + d], acc);   // sc broadcast, v coalesced
    }
    red[g][d] = acc;
    __syncthreads();
    if (t < 64) {
        float o = ((red[0][t] + red[1][t]) + (red[2][t] + red[3][t])) * inv;
        int b = bh >> 3, h = bh & 7;
        // (B,H,C,D) -> (B,C,H*D) transpose happens here
        oa[(b * 256 + i) * 512 + h * 64 + t] = o;
    }
}

// ---------------------------------------------------------------------------
extern "C" void kernel_launch(void* const* d_in, const int* in_sizes, int n_in,
                              void* d_out, int out_size, void* d_ws, size_t ws_size,
                              hipStream_t stream) {
    const float* x  = (const float*)d_in[0];
    const float* Wq = (const float*)d_in[1];
    const float* bq = (const float*)d_in[2];
    const float* Wk = (const float*)d_in[3];
    const float* bk = (const float*)d_in[4];
    const float* Wv = (const float*)d_in[5];
    const float* bv = (const float*)d_in[6];
    const float* w1 = (const float*)d_in[7];
    const float* b1 = (const float*)d_in[8];
    const float* w2 = (const float*)d_in[9];
    const float* b2 = (const float*)d_in[10];
    const float* Wo = (const float*)d_in[11];
    const float* bo = (const float*)d_in[12];
    float* out = (float*)d_out;

    // workspace: 6 buffers of B*H*C*D = 262144 floats (1 MiB) each = 6 MiB
    float* qb  = (float*)d_ws;
    float* kb  = qb  + 262144;
    float* vb  = kb  + 262144;
    float* qpb = vb  + 262144;
    float* kpb = qpb + 262144;
    float* oab = kpb + 262144;

    // 1) QKV projections into (B,H,C,D)
    mm_nt_kernel<<<dim3(8, 8, 3), 256, 0, stream>>>(
        x, Wq, bq, qb, Wk, bk, kb, Wv, bv, vb, 1);
    // 2) q_p + b1 and k_p
    qp_kp_kernel<<<dim3(1024), 256, 0, stream>>>(qb, kb, w1, b1, qpb, kpb);
    // 3) fused second-order scores + top-64 + softmax + attn@V
    fused_attn_kernel<<<dim3(256, 16), 256, 0, stream>>>(
        qb, kb, vb, qpb, kpb, w1, w2, b2, oab);
    // 4) output projection
    mm_nt_kernel<<<dim3(8, 8, 1), 256, 0, stream>>>(
        oab, Wo, bo, out, nullptr, nullptr, nullptr, nullptr, nullptr, nullptr, 0);
}

// Round 3
// 254.877 us; speedup vs baseline: 2.2884x; 2.2884x over previous
//
#include <hip/hip_runtime.h>
#include <math.h>

// Problem constants: B=2, C=256, DM=512, H=8, D=64, SPARSE_K=64
typedef __bf16 bf16;
typedef __attribute__((ext_vector_type(4))) __bf16 bf16x4;
typedef __attribute__((ext_vector_type(8))) __bf16 bf16x8;
typedef __attribute__((ext_vector_type(4))) float floatx4;

// ---------------------------------------------------------------------------
// Generic C = A @ W^T + bias.  A: M x 512 row-major. W: 512 x 512 row-major.
// blockIdx.z selects among up to 3 (W, bias, out) triples (QKV fusion).
// heads_mode=1: scatter output (b,c,E) -> q[b][h][c][d] layout.
// ---------------------------------------------------------------------------
__global__ __launch_bounds__(256) void mm_nt_kernel(
    const float* __restrict__ A,
    const float* __restrict__ Wa, const float* __restrict__ ba, float* __restrict__ outa,
    const float* __restrict__ Wb, const float* __restrict__ bb, float* __restrict__ outb,
    const float* __restrict__ Wc, const float* __restrict__ bc, float* __restrict__ outc,
    int heads_mode)
{
    const float* W = Wa; const float* bias = ba; float* out = outa;
    if (blockIdx.z == 1) { W = Wb; bias = bb; out = outb; }
    if (blockIdx.z == 2) { W = Wc; bias = bc; out = outc; }

    __shared__ float As[16][64];   // [k][m]
    __shared__ float Ws[16][64];   // [k][n]

    const int m0 = blockIdx.y * 64;
    const int n0 = blockIdx.x * 64;
    const int t  = threadIdx.x;
    const int tx = t & 15;
    const int ty = t >> 4;
    const int lr = t >> 2;
    const int lc = (t & 3) * 4;

    float acc[4][4] = {};

    for (int k0 = 0; k0 < 512; k0 += 16) {
        float4 av = *(const float4*)&A[(m0 + lr) * 512 + k0 + lc];
        float4 wv = *(const float4*)&W[(n0 + lr) * 512 + k0 + lc];
        As[lc + 0][lr] = av.x; As[lc + 1][lr] = av.y;
        As[lc + 2][lr] = av.z; As[lc + 3][lr] = av.w;
        Ws[lc + 0][lr] = wv.x; Ws[lc + 1][lr] = wv.y;
        Ws[lc + 2][lr] = wv.z; Ws[lc + 3][lr] = wv.w;
        __syncthreads();
        #pragma unroll
        for (int kk = 0; kk < 16; kk++) {
            float a4[4], w4[4];
            #pragma unroll
            for (int u = 0; u < 4; u++) a4[u] = As[kk][ty * 4 + u];
            #pragma unroll
            for (int u = 0; u < 4; u++) w4[u] = Ws[kk][tx * 4 + u];
            #pragma unroll
            for (int um = 0; um < 4; um++)
                #pragma unroll
                for (int un = 0; un < 4; un++)
                    acc[um][un] = fmaf(a4[um], w4[un], acc[um][un]);
        }
        __syncthreads();
    }

    #pragma unroll
    for (int um = 0; um < 4; um++) {
        int m = m0 + ty * 4 + um;
        #pragma unroll
        for (int un = 0; un < 4; un++) {
            int n = n0 + tx * 4 + un;
            float val = acc[um][un] + bias[n];
            if (heads_mode) {
                int b = m >> 8, c = m & 255, h = n >> 6, d = n & 63;
                out[(((b << 3) + h) * 256 + c) * 64 + d] = val;
            } else {
                out[m * 512 + n] = val;
            }
        }
    }
}

// ---------------------------------------------------------------------------
// Split K (fp32, [4096][64]) into hi/mid/lo bf16 (a = h + m + l, rep err
// ~2^-27) stored in MFMA frag-major order:
// k*[((bh*16 + jtg)*2 + ks)*512 + (q4*16 + mm)*8 + u]
//   holds K[bh*256 + jtg*16 + mm][ks*32 + q4*8 + u]
// so a wave's fragment load is 64 lanes x 16 B fully contiguous.
// ---------------------------------------------------------------------------
__global__ __launch_bounds__(256) void split_k_kernel(
    const float* __restrict__ kb,
    bf16* __restrict__ khi, bf16* __restrict__ kmid, bf16* __restrict__ klo)
{
    int t = blockIdx.x * 256 + threadIdx.x;     // 65536 threads, 4 elems each
    int row = t >> 4;                           // bh*256 + j
    int e0  = (t & 15) * 4;
    int bh = row >> 8, j = row & 255;
    int jtg = j >> 4, mm = j & 15;
    int ks = e0 >> 5, q4 = (e0 >> 3) & 3, u0 = e0 & 7;
    int dst = (((bh * 16 + jtg) * 2 + ks) * 64 + q4 * 16 + mm) * 8 + u0;
    float4 vv = *(const float4*)&kb[row * 64 + e0];
    float a4[4] = {vv.x, vv.y, vv.z, vv.w};
    bf16x4 h, m, l;
    #pragma unroll
    for (int u = 0; u < 4; u++) {
        float a = a4[u];
        bf16 hh = (bf16)a;  float r1 = a - (float)hh;
        bf16 mm2 = (bf16)r1; float r2 = r1 - (float)mm2;
        h[u] = hh; m[u] = mm2; l[u] = (bf16)r2;
    }
    *(bf16x4*)&khi[dst]  = h;
    *(bf16x4*)&kmid[dst] = m;
    *(bf16x4*)&klo[dst]  = l;
}

// ---------------------------------------------------------------------------
// Fused per-(bh,i): res[j,f] = qpb_i[f] + sum_e K[j,e]*(w1b[f,e]+w1c[f,e]*q_i[e])
// via triple-split bf16 MFMA (6 products: hh, hm, mh, hl, lh, mm -> rel err
// ~3e-8, below the fp32 reference's own rounding noise), then
// gelu -> w2 dot -> scores -> top-64 threshold -> softmax -> attn @ V.
// Grid (i=256, bh=16), 256 threads = 4 waves; wave wv owns j in [wv*64, wv*64+64).
// ---------------------------------------------------------------------------
__global__ __launch_bounds__(256, 2) void fused_mfma_attn_kernel(
    const float* __restrict__ q, const float* __restrict__ v,
    const bf16* __restrict__ khi, const bf16* __restrict__ kmid, const bf16* __restrict__ klo,
    const float* __restrict__ w1, const float* __restrict__ b1,
    const float* __restrict__ w2, const float* __restrict__ b2,
    float* __restrict__ oa)
{
    const int i  = blockIdx.x;
    const int bh = blockIdx.y;
    const int t  = threadIdx.x;
    const int lane = t & 63;
    const int wv   = t >> 6;
    const int m    = lane & 15;
    const int q4   = lane >> 4;

    __shared__ bf16 sAhi[4096];       // frag-major A_i hi
    __shared__ bf16 sAmid[4096];      // frag-major A_i mid
    __shared__ bf16 sAlo[4096];       // frag-major A_i lo
    __shared__ float qpb_part[64][4];
    __shared__ float qpb_s[64];
    __shared__ float sc[256];
    __shared__ float red[4][64];
    __shared__ float red2[4];
    __shared__ float thresh_s;

    const float* qrow = q + (bh * 256 + i) * 64;   // block-uniform

    // ---- build A_i = w1b + w1c * q_i (hi/mid/lo bf16, frag-major) + qpb partials
    {
        int f   = t >> 2;               // 0..63
        int ec0 = (t & 3) * 16;         // e chunk start
        const float* w1row = w1 + f * 192;
        float qa = 0.f;
        #pragma unroll
        for (int c = 0; c < 2; c++) {   // two 8-wide e sub-chunks
            bf16x8 h8, m8, l8;
            #pragma unroll
            for (int u = 0; u < 2; u++) {
                int e = ec0 + c * 8 + u * 4;
                float4 wa = *(const float4*)&w1row[e];
                float4 wb = *(const float4*)&w1row[64 + e];
                float4 wc = *(const float4*)&w1row[128 + e];
                float4 qv = *(const float4*)&qrow[e];
                qa += wa.x * qv.x + wa.y * qv.y + wa.z * qv.z + wa.w * qv.w;
                float av[4];
                av[0] = fmaf(wc.x, qv.x, wb.x);
                av[1] = fmaf(wc.y, qv.y, wb.y);
                av[2] = fmaf(wc.z, qv.z, wb.z);
                av[3] = fmaf(wc.w, qv.w, wb.w);
                #pragma unroll
                for (int uu = 0; uu < 4; uu++) {
                    float a = av[uu];
                    bf16 hh = (bf16)a;   float r1 = a - (float)hh;
                    bf16 mm2 = (bf16)r1; float r2 = r1 - (float)mm2;
                    h8[u * 4 + uu] = hh;
                    m8[u * 4 + uu] = mm2;
                    l8[u * 4 + uu] = (bf16)r2;
                }
            }
            int e0c = ec0 + c * 8;
            int ks = e0c >> 5, qq = (e0c >> 3) & 3;
            int ft = f >> 4, fm = f & 15;
            int dst = ((ks * 4 + ft) * 64 + qq * 16 + fm) * 8;
            *(bf16x8*)&sAhi[dst]  = h8;
            *(bf16x8*)&sAmid[dst] = m8;
            *(bf16x8*)&sAlo[dst]  = l8;
        }
        qpb_part[f][t & 3] = qa;
    }
    __syncthreads();
    if (t < 64) {
        qpb_s[t] = b1[t] + ((qpb_part[t][0] + qpb_part[t][1]) +
                            (qpb_part[t][2] + qpb_part[t][3]));
    }
    __syncthreads();

    // ---- MFMA: res[j, f], M=j (K rows as A-operand), N=f (A_i rows as B-operand)
    floatx4 acc[4][4];
    #pragma unroll
    for (int jt = 0; jt < 4; jt++)
        #pragma unroll
        for (int ft = 0; ft < 4; ft++) {
            float qv = qpb_s[ft * 16 + m];
            acc[jt][ft][0] = qv; acc[jt][ft][1] = qv;
            acc[jt][ft][2] = qv; acc[jt][ft][3] = qv;
        }

    #pragma unroll
    for (int ks = 0; ks < 2; ks++) {
        bf16x8 Ah[4], Am[4], Al[4];
        #pragma unroll
        for (int ft = 0; ft < 4; ft++) {
            int src = ((ks * 4 + ft) * 64 + lane) * 8;
            Ah[ft] = *(bf16x8*)&sAhi[src];
            Am[ft] = *(bf16x8*)&sAmid[src];
            Al[ft] = *(bf16x8*)&sAlo[src];
        }
        #pragma unroll
        for (int jt = 0; jt < 4; jt++) {
            int src = (((bh * 16 + wv * 4 + jt) * 2 + ks) * 64 + lane) * 8;
            bf16x8 Kh = *(const bf16x8*)&khi[src];
            bf16x8 Km = *(const bf16x8*)&kmid[src];
            bf16x8 Kl = *(const bf16x8*)&klo[src];
            #pragma unroll
            for (int ft = 0; ft < 4; ft++) {
                acc[jt][ft] = __builtin_amdgcn_mfma_f32_16x16x32_bf16(Kh, Ah[ft], acc[jt][ft], 0, 0, 0);
                acc[jt][ft] = __builtin_amdgcn_mfma_f32_16x16x32_bf16(Kh, Am[ft], acc[jt][ft], 0, 0, 0);
                acc[jt][ft] = __builtin_amdgcn_mfma_f32_16x16x32_bf16(Km, Ah[ft], acc[jt][ft], 0, 0, 0);
                acc[jt][ft] = __builtin_amdgcn_mfma_f32_16x16x32_bf16(Kh, Al[ft], acc[jt][ft], 0, 0, 0);
                acc[jt][ft] = __builtin_amdgcn_mfma_f32_16x16x32_bf16(Kl, Ah[ft], acc[jt][ft], 0, 0, 0);
                acc[jt][ft] = __builtin_amdgcn_mfma_f32_16x16x32_bf16(Km, Am[ft], acc[jt][ft], 0, 0, 0);
            }
        }
    }

    // ---- epilogue: gelu + w2-dot, reduce over f (cols) -> scores
    const float b2v = b2[0];
    float w2v[4];
    #pragma unroll
    for (int ft = 0; ft < 4; ft++) w2v[ft] = w2[ft * 16 + m];

    #pragma unroll
    for (int jt = 0; jt < 4; jt++) {
        float part[4];
        #pragma unroll
        for (int r = 0; r < 4; r++) {
            float s = 0.f;
            #pragma unroll
            for (int ft = 0; ft < 4; ft++) {
                float x = acc[jt][ft][r];
                float g = 0.5f * x * (1.0f + erff(x * 0.70710678118654752440f));
                s = fmaf(w2v[ft], g, s);
            }
            // reduce across the 16 lanes holding the f-columns
            #pragma unroll
            for (int mask = 1; mask < 16; mask <<= 1)
                s += __shfl_xor(s, mask);
            part[r] = s;
        }
        float outv = part[0];
        outv = (m == 1) ? part[1] : outv;
        outv = (m == 2) ? part[2] : outv;
        outv = (m == 3) ? part[3] : outv;
        if (m < 4) {
            int j = wv * 64 + jt * 16 + q4 * 4 + m;
            sc[j] = (outv + b2v) * 0.125f;
        }
    }
    __syncthreads();

    // ---- top-64 threshold (rank-count, tie-exact) + row max
    float score = sc[t];
    int cnt = 0, eq = 0;
    float smax = -3.0e38f;
    for (int m4 = 0; m4 < 64; m4++) {
        float4 s4 = *(const float4*)&sc[m4 * 4];
        cnt += (s4.x > score) + (s4.y > score) + (s4.z > score) + (s4.w > score);
        eq  += (s4.x == score) + (s4.y == score) + (s4.z == score) + (s4.w == score);
        smax = fmaxf(smax, fmaxf(fmaxf(s4.x, s4.y), fmaxf(s4.z, s4.w)));
    }
    if (cnt < 64 && cnt + eq >= 64) thresh_s = score;   // same value from all qualifiers
    __syncthreads();

    const float thr = thresh_s;
    float p = (score >= thr) ? __expf(score - smax) : 0.0f;
    sc[t] = p;                       // all scan reads completed before the barrier
    float ps = p;
    #pragma unroll
    for (int mask = 1; mask < 64; mask <<= 1) ps += __shfl_xor(ps, mask);
    if (lane == 0) red2[wv] = ps;
    __syncthreads();
    const float inv = 1.0f / (((red2[0] + red2[1]) + (red2[2] + red2[3])));

    // ---- attn @ V
    const int d = t & 63, g = t >> 6;
    const float* vb = v + bh * 256 * 64;
    float a0 = 0.f;
    for (int j4 = 0; j4 < 16; j4++) {
        int jj = g * 64 + j4 * 4;
        float4 p4 = *(const float4*)&sc[jj];
        a0 = fmaf(p4.x, vb[(jj + 0) * 64 + d], a0);
        a0 = fmaf(p4.y, vb[(jj + 1) * 64 + d], a0);
        a0 = fmaf(p4.z, vb[(jj + 2) * 64 + d], a0);
        a0 = fmaf(p4.w, vb[(jj + 3) * 64 + d], a0);
    }
    red[g][d] = a0;
    __syncthreads();
    if (t < 64) {
        float o = ((red[0][t] + red[1][t]) + (red[2][t] + red[3][t])) * inv;
        int b = bh >> 3, h = bh & 7;
        oa[(b * 256 + i) * 512 + h * 64 + t] = o;   // (B,H,C,D)->(B,C,DM)
    }
}

// ---------------------------------------------------------------------------
extern "C" void kernel_launch(void* const* d_in, const int* in_sizes, int n_in,
                              void* d_out, int out_size, void* d_ws, size_t ws_size,
                              hipStream_t stream) {
    const float* x  = (const float*)d_in[0];
    const float* Wq = (const float*)d_in[1];
    const float* bq = (const float*)d_in[2];
    const float* Wk = (const float*)d_in[3];
    const float* bk = (const float*)d_in[4];
    const float* Wv = (const float*)d_in[5];
    const float* bv = (const float*)d_in[6];
    const float* w1 = (const float*)d_in[7];
    const float* b1 = (const float*)d_in[8];
    const float* w2 = (const float*)d_in[9];
    const float* b2 = (const float*)d_in[10];
    const float* Wo = (const float*)d_in[11];
    const float* bo = (const float*)d_in[12];
    float* out = (float*)d_out;

    // workspace layout
    float* qb  = (float*)d_ws;          // 1 MiB each (262144 floats)
    float* kb  = qb  + 262144;
    float* vb  = kb  + 262144;
    float* oab = vb  + 262144;
    bf16*  khi = (bf16*)(oab + 262144); // 512 KiB each
    bf16*  kmid = khi + 262144;
    bf16*  klo  = kmid + 262144;

    // 1) QKV projections into (B,H,C,D)
    mm_nt_kernel<<<dim3(8, 8, 3), 256, 0, stream>>>(
        x, Wq, bq, qb, Wk, bk, kb, Wv, bv, vb, 1);
    // 2) split K into frag-major bf16 hi/mid/lo
    split_k_kernel<<<dim3(256), 256, 0, stream>>>(kb, khi, kmid, klo);
    // 3) fused second-order scores (MFMA) + top-64 + softmax + attn@V
    fused_mfma_attn_kernel<<<dim3(256, 16), 256, 0, stream>>>(
        qb, vb, khi, kmid, klo, w1, b1, w2, b2, oab);
    // 4) output projection
    mm_nt_kernel<<<dim3(8, 8, 1), 256, 0, stream>>>(
        oab, Wo, bo, out, nullptr, nullptr, nullptr, nullptr, nullptr, nullptr, 0);
}

// Round 4
// 233.868 us; speedup vs baseline: 2.4939x; 1.0898x over previous
//
#include <hip/hip_runtime.h>
#include <math.h>

// Problem constants: B=2, C=256, DM=512, H=8, D=64, SPARSE_K=64
typedef __bf16 bf16;
typedef __attribute__((ext_vector_type(4))) __bf16 bf16x4;
typedef __attribute__((ext_vector_type(8))) __bf16 bf16x8;
typedef __attribute__((ext_vector_type(4))) float floatx4;

// ---------------------------------------------------------------------------
// Exact gelu: 6-term Taylor erf on |t|<=0.5 (abs err <= 1.5e-8), erff fallback
// for rare outliers (res sigma ~0.11 -> P(|t|>0.5) ~ 4e-6).
// ---------------------------------------------------------------------------
__device__ __forceinline__ float gelu_exact(float x) {
    float tt = x * 0.70710678118654752440f;
    float e;
    if (__builtin_expect(fabsf(tt) > 0.5f, 0)) {
        e = erff(tt);
    } else {
        float s = tt * tt;
        e = tt * fmaf(s, fmaf(s, fmaf(s, fmaf(s, fmaf(s,
                -8.548327023450852e-4f, 5.223977625442188e-3f),
                -2.6866170645131252e-2f), 0.11283791670955126f),
                -0.3761263890318375f), 1.1283791670955126f);
    }
    return 0.5f * x * (1.0f + e);
}

// ---------------------------------------------------------------------------
// Triple-split (a = h+m+l bf16, rep err ~2^-27) into MFMA frag-major order
// for [512][512] matrices; up to 5 matrices batched via blockIdx.z.
// Element (row,k) -> dst ((rt*16 + ks)*64 + q4*16 + rm)*8 + u,
// rt=row>>4, rm=row&15, ks=k>>5, q4=(k>>3)&3, u=k&7.
// ---------------------------------------------------------------------------
struct SplitArgs {
    const float* src[5];
    bf16* h[5]; bf16* m[5]; bf16* l[5];
};

__global__ __launch_bounds__(256) void split3_512_kernel(SplitArgs S) {
    int z = blockIdx.z;
    const float* src = S.src[z];
    bf16* dh = S.h[z]; bf16* dm = S.m[z]; bf16* dl = S.l[z];
    int t = blockIdx.x * 256 + threadIdx.x;   // 65536 threads, 4 elems each
    int row = t >> 7, kq = (t & 127) * 4;
    int rt = row >> 4, rm = row & 15;
    int ks = kq >> 5, q4 = (kq >> 3) & 3, u0 = kq & 7;
    int dst = ((rt * 16 + ks) * 64 + q4 * 16 + rm) * 8 + u0;
    float4 vv = *(const float4*)&src[row * 512 + kq];
    float a4[4] = {vv.x, vv.y, vv.z, vv.w};
    bf16x4 h, m, l;
    #pragma unroll
    for (int u = 0; u < 4; u++) {
        float a = a4[u];
        bf16 hh = (bf16)a;  float r1 = a - (float)hh;
        bf16 mm = (bf16)r1; float r2 = r1 - (float)mm;
        h[u] = hh; m[u] = mm; l[u] = (bf16)r2;
    }
    *(bf16x4*)&dh[dst] = h;
    *(bf16x4*)&dm[dst] = m;
    *(bf16x4*)&dl[dst] = l;
}

// ---------------------------------------------------------------------------
// Same split for K (fp32, [4096][64]) -> frag-major (Kd=64 -> 2 k-chunks).
// ---------------------------------------------------------------------------
__global__ __launch_bounds__(256) void split_k_kernel(
    const float* __restrict__ kb,
    bf16* __restrict__ khi, bf16* __restrict__ kmid, bf16* __restrict__ klo)
{
    int t = blockIdx.x * 256 + threadIdx.x;     // 65536 threads, 4 elems each
    int row = t >> 4;                           // bh*256 + j
    int e0  = (t & 15) * 4;
    int rt = row >> 4, rm = row & 15;
    int ks = e0 >> 5, q4 = (e0 >> 3) & 3, u0 = e0 & 7;
    int dst = ((rt * 2 + ks) * 64 + q4 * 16 + rm) * 8 + u0;
    float4 vv = *(const float4*)&kb[row * 64 + e0];
    float a4[4] = {vv.x, vv.y, vv.z, vv.w};
    bf16x4 h, m, l;
    #pragma unroll
    for (int u = 0; u < 4; u++) {
        float a = a4[u];
        bf16 hh = (bf16)a;  float r1 = a - (float)hh;
        bf16 mm = (bf16)r1; float r2 = r1 - (float)mm;
        h[u] = hh; m[u] = mm; l[u] = (bf16)r2;
    }
    *(bf16x4*)&khi[dst]  = h;
    *(bf16x4*)&kmid[dst] = m;
    *(bf16x4*)&klo[dst]  = l;
}

// ---------------------------------------------------------------------------
// C = A @ W^T + bias via triple-split bf16 MFMA (6 terms: hh,hm,mh,hl,lh,mm;
// rel err ~3e-8). A,W pre-split frag-major [rt][ks][64][8]. 64x64 tile/block,
// wave w = m-tile, 4 n-tiles. blockIdx.z selects (W,bias,out) triple.
// heads_mode=1 scatters (b,c,E) -> (b,h,c,d).
// ---------------------------------------------------------------------------
struct MMArgs {
    const bf16 *Ah, *Am, *Al;
    const bf16 *Wh0,*Wm0,*Wl0, *Wh1,*Wm1,*Wl1, *Wh2,*Wm2,*Wl2;
    const float *b0, *b1, *b2;
    float *o0, *o1, *o2;
    int heads_mode;
};

__global__ __launch_bounds__(256) void mm_mfma_kernel(MMArgs A) {
    const bf16 *Wh = A.Wh0, *Wm = A.Wm0, *Wl = A.Wl0;
    const float* bias = A.b0; float* out = A.o0;
    if (blockIdx.z == 1) { Wh=A.Wh1; Wm=A.Wm1; Wl=A.Wl1; bias=A.b1; out=A.o1; }
    if (blockIdx.z == 2) { Wh=A.Wh2; Wm=A.Wm2; Wl=A.Wl2; bias=A.b2; out=A.o2; }

    const int t = threadIdx.x;
    const int lane = t & 63, w = t >> 6;
    const int m16 = lane & 15, q4 = lane >> 4;
    const int bx = blockIdx.x, by = blockIdx.y;
    const int rta = by * 4 + w;

    floatx4 acc[4];
    #pragma unroll
    for (int nt = 0; nt < 4; nt++) {
        float bv = bias[bx * 64 + nt * 16 + m16];
        acc[nt][0] = bv; acc[nt][1] = bv; acc[nt][2] = bv; acc[nt][3] = bv;
    }

    #pragma unroll 2
    for (int ks = 0; ks < 16; ks++) {
        int sa = ((rta * 16 + ks) * 64 + lane) * 8;
        bf16x8 ah = *(const bf16x8*)&A.Ah[sa];
        bf16x8 am = *(const bf16x8*)&A.Am[sa];
        bf16x8 al = *(const bf16x8*)&A.Al[sa];
        #pragma unroll
        for (int nt = 0; nt < 4; nt++) {
            int sw = (((bx * 4 + nt) * 16 + ks) * 64 + lane) * 8;
            bf16x8 wh = *(const bf16x8*)&Wh[sw];
            bf16x8 wm = *(const bf16x8*)&Wm[sw];
            bf16x8 wl = *(const bf16x8*)&Wl[sw];
            acc[nt] = __builtin_amdgcn_mfma_f32_16x16x32_bf16(ah, wh, acc[nt], 0, 0, 0);
            acc[nt] = __builtin_amdgcn_mfma_f32_16x16x32_bf16(ah, wm, acc[nt], 0, 0, 0);
            acc[nt] = __builtin_amdgcn_mfma_f32_16x16x32_bf16(am, wh, acc[nt], 0, 0, 0);
            acc[nt] = __builtin_amdgcn_mfma_f32_16x16x32_bf16(ah, wl, acc[nt], 0, 0, 0);
            acc[nt] = __builtin_amdgcn_mfma_f32_16x16x32_bf16(al, wh, acc[nt], 0, 0, 0);
            acc[nt] = __builtin_amdgcn_mfma_f32_16x16x32_bf16(am, wm, acc[nt], 0, 0, 0);
        }
    }

    #pragma unroll
    for (int nt = 0; nt < 4; nt++) {
        int n = bx * 64 + nt * 16 + m16;
        #pragma unroll
        for (int r = 0; r < 4; r++) {
            int m = by * 64 + w * 16 + q4 * 4 + r;
            float val = acc[nt][r];
            if (A.heads_mode) {
                out[(((m >> 8) * 8 + (n >> 6)) * 256 + (m & 255)) * 64 + (n & 63)] = val;
            } else {
                out[m * 512 + n] = val;
            }
        }
    }
}

// ---------------------------------------------------------------------------
// Fused per-(bh,i): res[j,f] = qpb_i[f] + sum_e K[j,e]*(w1b[f,e]+w1c[f,e]*q_i[e])
// via triple-split bf16 MFMA, then gelu -> w2 dot -> scores -> top-64 via
// 256-wide bitonic sort -> softmax -> attn @ V.
// ---------------------------------------------------------------------------
__global__ __launch_bounds__(256, 2) void fused_mfma_attn_kernel(
    const float* __restrict__ q, const float* __restrict__ v,
    const bf16* __restrict__ khi, const bf16* __restrict__ kmid, const bf16* __restrict__ klo,
    const float* __restrict__ w1, const float* __restrict__ b1,
    const float* __restrict__ w2, const float* __restrict__ b2,
    float* __restrict__ oa)
{
    const int i  = blockIdx.x;
    const int bh = blockIdx.y;
    const int t  = threadIdx.x;
    const int lane = t & 63;
    const int wv   = t >> 6;
    const int m    = lane & 15;
    const int q4   = lane >> 4;

    __shared__ bf16 sAhi[4096];
    __shared__ bf16 sAmid[4096];
    __shared__ bf16 sAlo[4096];
    __shared__ float qpb_part[64][4];
    __shared__ float qpb_s[64];
    __shared__ float sc[256];
    __shared__ float red[4][64];     // also reused as bitonic cross-wave buffer
    __shared__ float red2[4];
    __shared__ float thresh_s;
    __shared__ float smax_s;

    const float* qrow = q + (bh * 256 + i) * 64;   // block-uniform

    // ---- build A_i = w1b + w1c * q_i (hi/mid/lo bf16, frag-major) + qpb partials
    {
        int f   = t >> 2;
        int ec0 = (t & 3) * 16;
        const float* w1row = w1 + f * 192;
        float qa = 0.f;
        #pragma unroll
        for (int c = 0; c < 2; c++) {
            bf16x8 h8, m8, l8;
            #pragma unroll
            for (int u = 0; u < 2; u++) {
                int e = ec0 + c * 8 + u * 4;
                float4 wa = *(const float4*)&w1row[e];
                float4 wb = *(const float4*)&w1row[64 + e];
                float4 wc = *(const float4*)&w1row[128 + e];
                float4 qv = *(const float4*)&qrow[e];
                qa += wa.x * qv.x + wa.y * qv.y + wa.z * qv.z + wa.w * qv.w;
                float av[4];
                av[0] = fmaf(wc.x, qv.x, wb.x);
                av[1] = fmaf(wc.y, qv.y, wb.y);
                av[2] = fmaf(wc.z, qv.z, wb.z);
                av[3] = fmaf(wc.w, qv.w, wb.w);
                #pragma unroll
                for (int uu = 0; uu < 4; uu++) {
                    float a = av[uu];
                    bf16 hh = (bf16)a;   float r1 = a - (float)hh;
                    bf16 mm2 = (bf16)r1; float r2 = r1 - (float)mm2;
                    h8[u * 4 + uu] = hh;
                    m8[u * 4 + uu] = mm2;
                    l8[u * 4 + uu] = (bf16)r2;
                }
            }
            int e0c = ec0 + c * 8;
            int ks = e0c >> 5, qq = (e0c >> 3) & 3;
            int ft = f >> 4, fm = f & 15;
            int dst = ((ks * 4 + ft) * 64 + qq * 16 + fm) * 8;
            *(bf16x8*)&sAhi[dst]  = h8;
            *(bf16x8*)&sAmid[dst] = m8;
            *(bf16x8*)&sAlo[dst]  = l8;
        }
        qpb_part[f][t & 3] = qa;
    }
    __syncthreads();
    if (t < 64) {
        qpb_s[t] = b1[t] + ((qpb_part[t][0] + qpb_part[t][1]) +
                            (qpb_part[t][2] + qpb_part[t][3]));
    }
    __syncthreads();

    // ---- MFMA: res[j, f]
    floatx4 acc[4][4];
    #pragma unroll
    for (int jt = 0; jt < 4; jt++)
        #pragma unroll
        for (int ft = 0; ft < 4; ft++) {
            float qv = qpb_s[ft * 16 + m];
            acc[jt][ft][0] = qv; acc[jt][ft][1] = qv;
            acc[jt][ft][2] = qv; acc[jt][ft][3] = qv;
        }

    #pragma unroll
    for (int ks = 0; ks < 2; ks++) {
        bf16x8 Ah[4], Am[4], Al[4];
        #pragma unroll
        for (int ft = 0; ft < 4; ft++) {
            int src = ((ks * 4 + ft) * 64 + lane) * 8;
            Ah[ft] = *(bf16x8*)&sAhi[src];
            Am[ft] = *(bf16x8*)&sAmid[src];
            Al[ft] = *(bf16x8*)&sAlo[src];
        }
        #pragma unroll
        for (int jt = 0; jt < 4; jt++) {
            int src = (((bh * 16 + wv * 4 + jt) * 2 + ks) * 64 + lane) * 8;
            bf16x8 Kh = *(const bf16x8*)&khi[src];
            bf16x8 Km = *(const bf16x8*)&kmid[src];
            bf16x8 Kl = *(const bf16x8*)&klo[src];
            #pragma unroll
            for (int ft = 0; ft < 4; ft++) {
                acc[jt][ft] = __builtin_amdgcn_mfma_f32_16x16x32_bf16(Kh, Ah[ft], acc[jt][ft], 0, 0, 0);
                acc[jt][ft] = __builtin_amdgcn_mfma_f32_16x16x32_bf16(Kh, Am[ft], acc[jt][ft], 0, 0, 0);
                acc[jt][ft] = __builtin_amdgcn_mfma_f32_16x16x32_bf16(Km, Ah[ft], acc[jt][ft], 0, 0, 0);
                acc[jt][ft] = __builtin_amdgcn_mfma_f32_16x16x32_bf16(Kh, Al[ft], acc[jt][ft], 0, 0, 0);
                acc[jt][ft] = __builtin_amdgcn_mfma_f32_16x16x32_bf16(Kl, Ah[ft], acc[jt][ft], 0, 0, 0);
                acc[jt][ft] = __builtin_amdgcn_mfma_f32_16x16x32_bf16(Km, Am[ft], acc[jt][ft], 0, 0, 0);
            }
        }
    }

    // ---- epilogue: gelu + w2-dot, reduce over f (cols) -> scores
    const float b2v = b2[0];
    float w2v[4];
    #pragma unroll
    for (int ft = 0; ft < 4; ft++) w2v[ft] = w2[ft * 16 + m];

    #pragma unroll
    for (int jt = 0; jt < 4; jt++) {
        float part[4];
        #pragma unroll
        for (int r = 0; r < 4; r++) {
            float s = 0.f;
            #pragma unroll
            for (int ft = 0; ft < 4; ft++) {
                float g = gelu_exact(acc[jt][ft][r]);
                s = fmaf(w2v[ft], g, s);
            }
            #pragma unroll
            for (int mask = 1; mask < 16; mask <<= 1)
                s += __shfl_xor(s, mask);
            part[r] = s;
        }
        float outv = part[0];
        outv = (m == 1) ? part[1] : outv;
        outv = (m == 2) ? part[2] : outv;
        outv = (m == 3) ? part[3] : outv;
        if (m < 4) {
            int j = wv * 64 + jt * 16 + q4 * 4 + m;
            sc[j] = (outv + b2v) * 0.125f;
        }
    }
    __syncthreads();

    // ---- top-64 threshold via 256-wide bitonic sort (ascending by thread idx).
    // sorted[192] = 64th largest value = jax top_vals[...,-1] (ties exact).
    const float score = sc[t];     // each thread reads/writes only its own slot
    float sv = score;
    float* sbuf = &red[0][0];
    #pragma unroll
    for (int k = 2; k <= 256; k <<= 1) {
        #pragma unroll
        for (int j = k >> 1; j >= 1; j >>= 1) {
            float pv;
            if (j >= 64) {
                sbuf[t] = sv;
                __syncthreads();
                pv = sbuf[t ^ j];
                __syncthreads();
            } else {
                pv = __shfl_xor(sv, j);
            }
            bool keepMin = (((t & j) == 0) == ((t & k) == 0));
            sv = keepMin ? fminf(sv, pv) : fmaxf(sv, pv);
        }
    }
    if (t == 192) thresh_s = sv;
    if (t == 255) smax_s = sv;
    __syncthreads();

    const float thr = thresh_s, smax = smax_s;
    float p = (score >= thr) ? __expf(score - smax) : 0.0f;
    sc[t] = p;
    float ps = p;
    #pragma unroll
    for (int mask = 1; mask < 64; mask <<= 1) ps += __shfl_xor(ps, mask);
    if (lane == 0) red2[wv] = ps;
    __syncthreads();
    const float inv = 1.0f / (((red2[0] + red2[1]) + (red2[2] + red2[3])));

    // ---- attn @ V
    const int d = t & 63, g = t >> 6;
    const float* vb = v + bh * 256 * 64;
    float a0 = 0.f;
    for (int j4 = 0; j4 < 16; j4++) {
        int jj = g * 64 + j4 * 4;
        float4 p4 = *(const float4*)&sc[jj];
        a0 = fmaf(p4.x, vb[(jj + 0) * 64 + d], a0);
        a0 = fmaf(p4.y, vb[(jj + 1) * 64 + d], a0);
        a0 = fmaf(p4.z, vb[(jj + 2) * 64 + d], a0);
        a0 = fmaf(p4.w, vb[(jj + 3) * 64 + d], a0);
    }
    red[g][d] = a0;
    __syncthreads();
    if (t < 64) {
        float o = ((red[0][t] + red[1][t]) + (red[2][t] + red[3][t])) * inv;
        int b = bh >> 3, h = bh & 7;
        oa[(b * 256 + i) * 512 + h * 64 + t] = o;   // (B,H,C,D)->(B,C,DM)
    }
}

// ---------------------------------------------------------------------------
extern "C" void kernel_launch(void* const* d_in, const int* in_sizes, int n_in,
                              void* d_out, int out_size, void* d_ws, size_t ws_size,
                              hipStream_t stream) {
    const float* x  = (const float*)d_in[0];
    const float* Wq = (const float*)d_in[1];
    const float* bq = (const float*)d_in[2];
    const float* Wk = (const float*)d_in[3];
    const float* bk = (const float*)d_in[4];
    const float* Wv = (const float*)d_in[5];
    const float* bv = (const float*)d_in[6];
    const float* w1 = (const float*)d_in[7];
    const float* b1 = (const float*)d_in[8];
    const float* w2 = (const float*)d_in[9];
    const float* b2 = (const float*)d_in[10];
    const float* Wo = (const float*)d_in[11];
    const float* bo = (const float*)d_in[12];
    float* out = (float*)d_out;

    const int NE = 262144;   // 512*512 elements
    float* qb  = (float*)d_ws;
    float* kb  = qb  + NE;
    float* vb  = kb  + NE;
    float* oab = vb  + NE;
    bf16* base = (bf16*)(oab + NE);
    // triples: K, x, Wq, Wk, Wv, Wo, oab
    bf16* khi  = base;           bf16* kmid = khi + NE;   bf16* klo = kmid + NE;
    bf16* xs   = klo  + NE;      // each following name is a hi/mid/lo triple
    bf16* wqs  = xs   + 3 * NE;
    bf16* wks  = wqs  + 3 * NE;
    bf16* wvs  = wks  + 3 * NE;
    bf16* wos  = wvs  + 3 * NE;
    bf16* oas  = wos  + 3 * NE;

    // 1) split x, Wq, Wk, Wv, Wo into frag-major bf16 triples
    {
        SplitArgs S;
        const float* srcs[5] = {x, Wq, Wk, Wv, Wo};
        bf16* dsts[5] = {xs, wqs, wks, wvs, wos};
        for (int z = 0; z < 5; z++) {
            S.src[z] = srcs[z];
            S.h[z] = dsts[z]; S.m[z] = dsts[z] + NE; S.l[z] = dsts[z] + 2 * NE;
        }
        split3_512_kernel<<<dim3(256, 1, 5), 256, 0, stream>>>(S);
    }
    // 2) QKV projections (MFMA) into (B,H,C,D)
    {
        MMArgs M;
        M.Ah = xs; M.Am = xs + NE; M.Al = xs + 2 * NE;
        M.Wh0 = wqs; M.Wm0 = wqs + NE; M.Wl0 = wqs + 2 * NE;
        M.Wh1 = wks; M.Wm1 = wks + NE; M.Wl1 = wks + 2 * NE;
        M.Wh2 = wvs; M.Wm2 = wvs + NE; M.Wl2 = wvs + 2 * NE;
        M.b0 = bq; M.b1 = bk; M.b2 = bv;
        M.o0 = qb; M.o1 = kb; M.o2 = vb;
        M.heads_mode = 1;
        mm_mfma_kernel<<<dim3(8, 8, 3), 256, 0, stream>>>(M);
    }
    // 3) split K into frag-major bf16 triple
    split_k_kernel<<<dim3(256), 256, 0, stream>>>(kb, khi, kmid, klo);
    // 4) fused second-order scores (MFMA) + top-64 (bitonic) + softmax + attn@V
    fused_mfma_attn_kernel<<<dim3(256, 16), 256, 0, stream>>>(
        qb, vb, khi, kmid, klo, w1, b1, w2, b2, oab);
    // 5) split attention output
    {
        SplitArgs S;
        for (int z = 0; z < 5; z++) {
            S.src[z] = oab;
            S.h[z] = oas; S.m[z] = oas + NE; S.l[z] = oas + 2 * NE;
        }
        split3_512_kernel<<<dim3(256, 1, 1), 256, 0, stream>>>(S);
    }
    // 6) output projection (MFMA)
    {
        MMArgs M;
        M.Ah = oas; M.Am = oas + NE; M.Al = oas + 2 * NE;
        M.Wh0 = wos; M.Wm0 = wos + NE; M.Wl0 = wos + 2 * NE;
        M.Wh1 = wos; M.Wm1 = wos; M.Wl1 = wos;
        M.Wh2 = wos; M.Wm2 = wos; M.Wl2 = wos;
        M.b0 = bo; M.b1 = bo; M.b2 = bo;
        M.o0 = out; M.o1 = out; M.o2 = out;
        M.heads_mode = 0;
        mm_mfma_kernel<<<dim3(8, 8, 1), 256, 0, stream>>>(M);
    }
}

// Round 6
// 213.322 us; speedup vs baseline: 2.7341x; 1.0963x over previous
//
#include <hip/hip_runtime.h>
#include <math.h>

// Problem constants: B=2, C=256, DM=512, H=8, D=64, SPARSE_K=64
typedef __bf16 bf16;
typedef __attribute__((ext_vector_type(4))) __bf16 bf16x4;
typedef __attribute__((ext_vector_type(8))) __bf16 bf16x8;
typedef __attribute__((ext_vector_type(4))) float floatx4;

// ---------------------------------------------------------------------------
// Exact gelu: 6-term Taylor erf on |t|<=0.5 (abs err <= 1.5e-8), erff fallback
// for rare outliers.
// ---------------------------------------------------------------------------
__device__ __forceinline__ float gelu_exact(float x) {
    float tt = x * 0.70710678118654752440f;
    float e;
    if (__builtin_expect(fabsf(tt) > 0.5f, 0)) {
        e = erff(tt);
    } else {
        float s = tt * tt;
        e = tt * fmaf(s, fmaf(s, fmaf(s, fmaf(s, fmaf(s,
                -8.548327023450852e-4f, 5.223977625442188e-3f),
                -2.6866170645131252e-2f), 0.11283791670955126f),
                -0.3761263890318375f), 1.1283791670955126f);
    }
    return 0.5f * x * (1.0f + e);
}

__device__ __forceinline__ void split3(float a, bf16& h, bf16& m, bf16& l) {
    h = (bf16)a;  float r1 = a - (float)h;
    m = (bf16)r1; float r2 = r1 - (float)m;
    l = (bf16)r2;
}

// ---------------------------------------------------------------------------
// Triple-split into MFMA frag-major order for [512][512] matrices; 5 matrices
// batched via blockIdx.z. (row,k) -> ((rt*16+ks)*64 + q4*16 + rm)*8 + u.
// ---------------------------------------------------------------------------
struct SplitArgs {
    const float* src[5];
    bf16* h[5]; bf16* m[5]; bf16* l[5];
};

__global__ __launch_bounds__(256) void split3_512_kernel(SplitArgs S) {
    int z = blockIdx.z;
    const float* src = S.src[z];
    bf16* dh = S.h[z]; bf16* dm = S.m[z]; bf16* dl = S.l[z];
    int t = blockIdx.x * 256 + threadIdx.x;
    int row = t >> 7, kq = (t & 127) * 4;
    int rt = row >> 4, rm = row & 15;
    int ks = kq >> 5, q4 = (kq >> 3) & 3, u0 = kq & 7;
    int dst = ((rt * 16 + ks) * 64 + q4 * 16 + rm) * 8 + u0;
    float4 vv = *(const float4*)&src[row * 512 + kq];
    float a4[4] = {vv.x, vv.y, vv.z, vv.w};
    bf16x4 h, m, l;
    #pragma unroll
    for (int u = 0; u < 4; u++) {
        bf16 hh, mm, ll;
        split3(a4[u], hh, mm, ll);
        h[u] = hh; m[u] = mm; l[u] = ll;
    }
    *(bf16x4*)&dh[dst] = h;
    *(bf16x4*)&dm[dst] = m;
    *(bf16x4*)&dl[dst] = l;
}

// ---------------------------------------------------------------------------
// C = A @ W^T + bias via triple-split bf16 MFMA. One wave per block; each
// block computes a 16(m) x 64(n) tile. grid (8 nx, 32 ny, nz).
// mode 0: plain fp32 [m*512+n]; mode 1: heads fp32 (b,h,c,d);
// mode 2: K written directly as frag-major split triple.
// ---------------------------------------------------------------------------
struct MM2Args {
    const bf16 *Ah, *Am, *Al;
    const bf16 *Wh[3], *Wm[3], *Wl[3];
    const float* bias[3];
    float* outf[3];
    bf16 *kh, *km, *kl;
    int mode[3];
};

__global__ __launch_bounds__(64) void mm_mfma_kernel(MM2Args A) {
    const int z = blockIdx.z;
    const bf16* Wh = A.Wh[z]; const bf16* Wm = A.Wm[z]; const bf16* Wl = A.Wl[z];
    const float* bias = A.bias[z];
    const int lane = threadIdx.x;
    const int m16 = lane & 15, q4 = lane >> 4;
    const int mt = blockIdx.y, bx = blockIdx.x;

    floatx4 acc[4];
    #pragma unroll
    for (int nt = 0; nt < 4; nt++) {
        float bv = bias[bx * 64 + nt * 16 + m16];
        acc[nt][0] = bv; acc[nt][1] = bv; acc[nt][2] = bv; acc[nt][3] = bv;
    }

    #pragma unroll 2
    for (int ks = 0; ks < 16; ks++) {
        int sa = ((mt * 16 + ks) * 64 + lane) * 8;
        bf16x8 ah = *(const bf16x8*)&A.Ah[sa];
        bf16x8 am = *(const bf16x8*)&A.Am[sa];
        bf16x8 al = *(const bf16x8*)&A.Al[sa];
        #pragma unroll
        for (int nt = 0; nt < 4; nt++) {
            int sw = (((bx * 4 + nt) * 16 + ks) * 64 + lane) * 8;
            bf16x8 wh = *(const bf16x8*)&Wh[sw];
            bf16x8 wm = *(const bf16x8*)&Wm[sw];
            bf16x8 wl = *(const bf16x8*)&Wl[sw];
            acc[nt] = __builtin_amdgcn_mfma_f32_16x16x32_bf16(ah, wh, acc[nt], 0, 0, 0);
            acc[nt] = __builtin_amdgcn_mfma_f32_16x16x32_bf16(ah, wm, acc[nt], 0, 0, 0);
            acc[nt] = __builtin_amdgcn_mfma_f32_16x16x32_bf16(am, wh, acc[nt], 0, 0, 0);
            acc[nt] = __builtin_amdgcn_mfma_f32_16x16x32_bf16(ah, wl, acc[nt], 0, 0, 0);
            acc[nt] = __builtin_amdgcn_mfma_f32_16x16x32_bf16(al, wh, acc[nt], 0, 0, 0);
            acc[nt] = __builtin_amdgcn_mfma_f32_16x16x32_bf16(am, wm, acc[nt], 0, 0, 0);
        }
    }

    const int mode = A.mode[z];
    #pragma unroll
    for (int nt = 0; nt < 4; nt++) {
        int n = bx * 64 + nt * 16 + m16;
        #pragma unroll
        for (int r = 0; r < 4; r++) {
            int m = mt * 16 + q4 * 4 + r;
            float val = acc[nt][r];
            if (mode == 0) {
                A.outf[z][m * 512 + n] = val;
            } else if (mode == 1) {
                A.outf[z][(((m >> 8) * 8 + (n >> 6)) * 256 + (m & 255)) * 64 + (n & 63)] = val;
            } else {
                int krow = ((m >> 8) * 8 + (n >> 6)) * 256 + (m & 255);
                int d = n & 63;
                int dst = (((krow >> 4) * 2 + (d >> 5)) * 64 + ((d >> 3) & 3) * 16 + (krow & 15)) * 8 + (d & 7);
                bf16 h, mm, l;
                split3(val, h, mm, l);
                A.kh[dst] = h; A.km[dst] = mm; A.kl[dst] = l;
            }
        }
    }
}

// ---------------------------------------------------------------------------
// Fused per-(bh, i-pair): res^T[f,j] = qpb_i[f] + sum_e A_i[f,e]*K[j,e],
// A_i = w1b + w1c*q_i built IN REGISTERS per wave (wave w owns f-tile w;
// lane layout is exactly the MFMA A-operand layout -> no LDS staging).
// Then gelu -> w2 dot (2 shfl + LDS partial) -> scores -> dual bitonic
// top-64 -> softmax -> attn@V -> output written as split triple (frag-major).
// Grid (128 i-pairs, 16 bh), 256 threads.
// ---------------------------------------------------------------------------
__global__ __launch_bounds__(256, 3) void fused_mfma_attn_kernel(
    const float* __restrict__ q, const float* __restrict__ v,
    const bf16* __restrict__ khi, const bf16* __restrict__ kmid, const bf16* __restrict__ klo,
    const float* __restrict__ w1, const float* __restrict__ b1,
    const float* __restrict__ w2, const float* __restrict__ b2,
    bf16* __restrict__ oh, bf16* __restrict__ om, bf16* __restrict__ ol)
{
    const int i2 = blockIdx.x;     // query pair: i = 2*i2 + i01
    const int bh = blockIdx.y;
    const int t  = threadIdx.x;
    const int lane = t & 63, w = t >> 6;
    const int m16 = lane & 15, q4 = lane >> 4;

    __shared__ float part[2][4][256];   // per-wave f-partials of scores
    __shared__ float sc[2][256];        // softmax probabilities
    __shared__ float qpb_s[2][64];
    __shared__ float sbuf[2][256];      // bitonic cross-wave exchange
    __shared__ float red[2][4][64];
    __shared__ float red2[2][4];
    __shared__ float thr_s[2], smax_s[2];

    const int f = w * 16 + m16;         // this lane's f (A-operand M index)
    const float* w1row = w1 + f * 192;

    // ---- build A_i fragments in registers + qpb
    bf16x8 Ah[2][2], Am[2][2], Al[2][2];
    #pragma unroll
    for (int i01 = 0; i01 < 2; i01++) {
        const float* qrow = q + (bh * 256 + i2 * 2 + i01) * 64;
        float qa = 0.f;
        #pragma unroll
        for (int ks = 0; ks < 2; ks++) {
            int e0 = ks * 32 + q4 * 8;
            #pragma unroll
            for (int u = 0; u < 2; u++) {
                int e = e0 + u * 4;
                float4 wa = *(const float4*)&w1row[e];
                float4 wb = *(const float4*)&w1row[64 + e];
                float4 wc = *(const float4*)&w1row[128 + e];
                float4 qv = *(const float4*)&qrow[e];
                qa += wa.x * qv.x + wa.y * qv.y + wa.z * qv.z + wa.w * qv.w;
                float av[4];
                av[0] = fmaf(wc.x, qv.x, wb.x);
                av[1] = fmaf(wc.y, qv.y, wb.y);
                av[2] = fmaf(wc.z, qv.z, wb.z);
                av[3] = fmaf(wc.w, qv.w, wb.w);
                #pragma unroll
                for (int uu = 0; uu < 4; uu++) {
                    bf16 h, m, l;
                    split3(av[uu], h, m, l);
                    Ah[i01][ks][u * 4 + uu] = h;
                    Am[i01][ks][u * 4 + uu] = m;
                    Al[i01][ks][u * 4 + uu] = l;
                }
            }
        }
        qa += __shfl_xor(qa, 16);
        qa += __shfl_xor(qa, 32);
        if (lane < 16) qpb_s[i01][w * 16 + lane] = qa + b1[w * 16 + lane];
    }
    __syncthreads();

    floatx4 qpbr[2];
    qpbr[0] = *(const floatx4*)&qpb_s[0][w * 16 + q4 * 4];
    qpbr[1] = *(const floatx4*)&qpb_s[1][w * 16 + q4 * 4];
    const float4 w2f = *(const float4*)&w2[w * 16 + q4 * 4];
    const float b2v = b2[0];

    // ---- main loop over j-tiles: MFMA + immediate epilogue (no barriers)
    #pragma unroll 2
    for (int jt = 0; jt < 16; jt++) {
        int base = ((bh * 16 + jt) * 2 * 64 + lane) * 8;
        bf16x8 Kh0 = *(const bf16x8*)&khi [base];
        bf16x8 Km0 = *(const bf16x8*)&kmid[base];
        bf16x8 Kl0 = *(const bf16x8*)&klo [base];
        bf16x8 Kh1 = *(const bf16x8*)&khi [base + 512];
        bf16x8 Km1 = *(const bf16x8*)&kmid[base + 512];
        bf16x8 Kl1 = *(const bf16x8*)&klo [base + 512];
        #pragma unroll
        for (int i01 = 0; i01 < 2; i01++) {
            floatx4 a = qpbr[i01];
            a = __builtin_amdgcn_mfma_f32_16x16x32_bf16(Ah[i01][0], Kh0, a, 0, 0, 0);
            a = __builtin_amdgcn_mfma_f32_16x16x32_bf16(Ah[i01][0], Km0, a, 0, 0, 0);
            a = __builtin_amdgcn_mfma_f32_16x16x32_bf16(Am[i01][0], Kh0, a, 0, 0, 0);
            a = __builtin_amdgcn_mfma_f32_16x16x32_bf16(Ah[i01][0], Kl0, a, 0, 0, 0);
            a = __builtin_amdgcn_mfma_f32_16x16x32_bf16(Al[i01][0], Kh0, a, 0, 0, 0);
            a = __builtin_amdgcn_mfma_f32_16x16x32_bf16(Am[i01][0], Km0, a, 0, 0, 0);
            a = __builtin_amdgcn_mfma_f32_16x16x32_bf16(Ah[i01][1], Kh1, a, 0, 0, 0);
            a = __builtin_amdgcn_mfma_f32_16x16x32_bf16(Ah[i01][1], Km1, a, 0, 0, 0);
            a = __builtin_amdgcn_mfma_f32_16x16x32_bf16(Am[i01][1], Kh1, a, 0, 0, 0);
            a = __builtin_amdgcn_mfma_f32_16x16x32_bf16(Ah[i01][1], Kl1, a, 0, 0, 0);
            a = __builtin_amdgcn_mfma_f32_16x16x32_bf16(Al[i01][1], Kh1, a, 0, 0, 0);
            a = __builtin_amdgcn_mfma_f32_16x16x32_bf16(Am[i01][1], Km1, a, 0, 0, 0);
            // epilogue: rows of a = 4 f's (q4*4+r), col = j = jt*16+m16
            float s = 0.f;
            s = fmaf(w2f.x, gelu_exact(a[0]), s);
            s = fmaf(w2f.y, gelu_exact(a[1]), s);
            s = fmaf(w2f.z, gelu_exact(a[2]), s);
            s = fmaf(w2f.w, gelu_exact(a[3]), s);
            s += __shfl_xor(s, 16);
            s += __shfl_xor(s, 32);
            if (lane < 16) part[i01][w][jt * 16 + lane] = s;
        }
    }
    __syncthreads();

    // ---- scores
    float score[2];
    #pragma unroll
    for (int i01 = 0; i01 < 2; i01++) {
        score[i01] = (((part[i01][0][t] + part[i01][1][t]) +
                       (part[i01][2][t] + part[i01][3][t])) + b2v) * 0.125f;
    }

    // ---- dual lockstep 256-wide bitonic sort; sorted[192] = 64th largest.
    float sv0 = score[0], sv1 = score[1];
    #pragma unroll
    for (int k = 2; k <= 256; k <<= 1) {
        #pragma unroll
        for (int j = k >> 1; j >= 1; j >>= 1) {
            float pv0, pv1;
            if (j >= 64) {
                sbuf[0][t] = sv0; sbuf[1][t] = sv1;
                __syncthreads();
                pv0 = sbuf[0][t ^ j]; pv1 = sbuf[1][t ^ j];
                __syncthreads();
            } else {
                pv0 = __shfl_xor(sv0, j);
                pv1 = __shfl_xor(sv1, j);
            }
            bool keepMin = (((t & j) == 0) == ((t & k) == 0));
            sv0 = keepMin ? fminf(sv0, pv0) : fmaxf(sv0, pv0);
            sv1 = keepMin ? fminf(sv1, pv1) : fmaxf(sv1, pv1);
        }
    }
    if (t == 192) { thr_s[0] = sv0; thr_s[1] = sv1; }
    if (t == 255) { smax_s[0] = sv0; smax_s[1] = sv1; }
    __syncthreads();

    // ---- softmax numerator + denominator
    float p0 = (score[0] >= thr_s[0]) ? __expf(score[0] - smax_s[0]) : 0.0f;
    float p1 = (score[1] >= thr_s[1]) ? __expf(score[1] - smax_s[1]) : 0.0f;
    sc[0][t] = p0; sc[1][t] = p1;
    float ps0 = p0, ps1 = p1;
    #pragma unroll
    for (int mask = 1; mask < 64; mask <<= 1) {
        ps0 += __shfl_xor(ps0, mask);
        ps1 += __shfl_xor(ps1, mask);
    }
    if (lane == 0) { red2[0][w] = ps0; red2[1][w] = ps1; }
    __syncthreads();
    const float inv0 = 1.0f / ((red2[0][0] + red2[0][1]) + (red2[0][2] + red2[0][3]));
    const float inv1 = 1.0f / ((red2[1][0] + red2[1][1]) + (red2[1][2] + red2[1][3]));

    // ---- attn @ V (v loads shared between the two i's)
    const int d = t & 63, g = t >> 6;
    const float* vb = v + bh * 256 * 64;
    float a0 = 0.f, a1 = 0.f;
    for (int j4 = 0; j4 < 16; j4++) {
        int jj = g * 64 + j4 * 4;
        float4 p40 = *(const float4*)&sc[0][jj];
        float4 p41 = *(const float4*)&sc[1][jj];
        float v0 = vb[(jj + 0) * 64 + d];
        float v1 = vb[(jj + 1) * 64 + d];
        float v2 = vb[(jj + 2) * 64 + d];
        float v3 = vb[(jj + 3) * 64 + d];
        a0 = fmaf(p40.x, v0, a0); a1 = fmaf(p41.x, v0, a1);
        a0 = fmaf(p40.y, v1, a0); a1 = fmaf(p41.y, v1, a1);
        a0 = fmaf(p40.z, v2, a0); a1 = fmaf(p41.z, v2, a1);
        a0 = fmaf(p40.w, v3, a0); a1 = fmaf(p41.w, v3, a1);
    }
    red[0][g][d] = a0; red[1][g][d] = a1;
    __syncthreads();

    // ---- output: (B,H,C,D)->(B,C,DM) row, written as split frag-major triple
    if (t < 128) {
        int i01 = t >> 6, dd = t & 63;
        float o = ((red[i01][0][dd] + red[i01][1][dd]) +
                   (red[i01][2][dd] + red[i01][3][dd])) * (i01 ? inv1 : inv0);
        int b = bh >> 3, h = bh & 7;
        int row = b * 256 + i2 * 2 + i01;
        int n = h * 64 + dd;
        int dst = (((row >> 4) * 16 + (n >> 5)) * 64 + ((n >> 3) & 3) * 16 + (row & 15)) * 8 + (n & 7);
        bf16 hh, mm, ll;
        split3(o, hh, mm, ll);
        oh[dst] = hh; om[dst] = mm; ol[dst] = ll;
    }
}

// ---------------------------------------------------------------------------
extern "C" void kernel_launch(void* const* d_in, const int* in_sizes, int n_in,
                              void* d_out, int out_size, void* d_ws, size_t ws_size,
                              hipStream_t stream) {
    const float* x  = (const float*)d_in[0];
    const float* Wq = (const float*)d_in[1];
    const float* bq = (const float*)d_in[2];
    const float* Wk = (const float*)d_in[3];
    const float* bk = (const float*)d_in[4];
    const float* Wv = (const float*)d_in[5];
    const float* bv = (const float*)d_in[6];
    const float* w1 = (const float*)d_in[7];
    const float* b1 = (const float*)d_in[8];
    const float* w2 = (const float*)d_in[9];
    const float* b2 = (const float*)d_in[10];
    const float* Wo = (const float*)d_in[11];
    const float* bo = (const float*)d_in[12];
    float* out = (float*)d_out;

    const int NE = 262144;   // 512*512
    float* qb  = (float*)d_ws;          // q (b,h,c,d) fp32
    float* vb  = qb + NE;               // v (b,h,c,d) fp32
    bf16* base = (bf16*)(vb + NE);
    bf16* khi  = base;            bf16* kmid = khi + NE;    bf16* klo = kmid + NE;
    bf16* xs   = klo + NE;        // hi/mid/lo triples follow
    bf16* wqs  = xs  + 3 * NE;
    bf16* wks  = wqs + 3 * NE;
    bf16* wvs  = wks + 3 * NE;
    bf16* wos  = wvs + 3 * NE;
    bf16* oas  = wos + 3 * NE;

    // 1) split x, Wq, Wk, Wv, Wo into frag-major bf16 triples
    {
        SplitArgs S;
        const float* srcs[5] = {x, Wq, Wk, Wv, Wo};
        bf16* dsts[5] = {xs, wqs, wks, wvs, wos};
        for (int z = 0; z < 5; z++) {
            S.src[z] = srcs[z];
            S.h[z] = dsts[z]; S.m[z] = dsts[z] + NE; S.l[z] = dsts[z] + 2 * NE;
        }
        split3_512_kernel<<<dim3(256, 1, 5), 256, 0, stream>>>(S);
    }
    // 2) QKV projections; K written directly as split frag-major triple
    {
        MM2Args M;
        M.Ah = xs; M.Am = xs + NE; M.Al = xs + 2 * NE;
        M.Wh[0] = wqs; M.Wm[0] = wqs + NE; M.Wl[0] = wqs + 2 * NE;
        M.Wh[1] = wks; M.Wm[1] = wks + NE; M.Wl[1] = wks + 2 * NE;
        M.Wh[2] = wvs; M.Wm[2] = wvs + NE; M.Wl[2] = wvs + 2 * NE;
        M.bias[0] = bq; M.bias[1] = bk; M.bias[2] = bv;
        M.outf[0] = qb; M.outf[1] = nullptr; M.outf[2] = vb;
        M.kh = khi; M.km = kmid; M.kl = klo;
        M.mode[0] = 1; M.mode[1] = 2; M.mode[2] = 1;
        mm_mfma_kernel<<<dim3(8, 32, 3), 64, 0, stream>>>(M);
    }
    // 3) fused second-order scores + top-64 + softmax + attn@V (+ split out)
    fused_mfma_attn_kernel<<<dim3(128, 16), 256, 0, stream>>>(
        qb, vb, khi, kmid, klo, w1, b1, w2, b2,
        oas, oas + NE, oas + 2 * NE);
    // 4) output projection
    {
        MM2Args M;
        M.Ah = oas; M.Am = oas + NE; M.Al = oas + 2 * NE;
        M.Wh[0] = wos; M.Wm[0] = wos + NE; M.Wl[0] = wos + 2 * NE;
        M.Wh[1] = wos; M.Wm[1] = wos; M.Wl[1] = wos;
        M.Wh[2] = wos; M.Wm[2] = wos; M.Wl[2] = wos;
        M.bias[0] = bo; M.bias[1] = bo; M.bias[2] = bo;
        M.outf[0] = out; M.outf[1] = out; M.outf[2] = out;
        M.kh = khi; M.km = kmid; M.kl = klo;
        M.mode[0] = 0; M.mode[1] = 0; M.mode[2] = 0;
        mm_mfma_kernel<<<dim3(8, 32, 1), 64, 0, stream>>>(M);
    }
}